// Round 2
// baseline (3940.957 us; speedup 1.0000x reference)
//
#include <hip/hip_runtime.h>
#include <hip/hip_bf16.h>
#include <math.h>

#define BB 2
#define CC 128
#define HH 60
#define WW 108
#define HWN (HH*WW)

// ---------------------------------------------------------------------------
// Transpose [B][C][HW] -> [B][HW][C]  (channel-last, level-0 pooled map)
// ---------------------------------------------------------------------------
__global__ void transpose_cl_k(const float* __restrict__ in, float* __restrict__ out) {
    int bn = blockIdx.x;            // b*HW + n
    int b  = bn / HWN;
    int n  = bn % HWN;
    int c  = threadIdx.x;           // 128 threads
    out[(size_t)bn * CC + c] = in[((size_t)b * CC + c) * HWN + n];
}

// ---------------------------------------------------------------------------
// 2x2 avg pool on channel-last maps: [B][Hi][Wi][C] -> [B][Ho][Wo][C]
// ---------------------------------------------------------------------------
__global__ void pool_k(const float* __restrict__ in, float* __restrict__ out,
                       int Hi, int Wi, int Ho, int Wo) {
    int bp = blockIdx.x;            // b*Ho*Wo + p
    int b  = bp / (Ho * Wo);
    int p  = bp % (Ho * Wo);
    int yo = p / Wo, xo = p % Wo;
    int c  = threadIdx.x;           // 128 threads
    const float* i0 = in + (((size_t)b * Hi + 2 * yo) * Wi + 2 * xo) * CC;
    float v = i0[c] + i0[CC + c] + i0[(size_t)Wi * CC + c] + i0[(size_t)Wi * CC + CC + c];
    out[(((size_t)b * Ho + yo) * Wo + xo) * CC + c] = 0.25f * v;
}

// ---------------------------------------------------------------------------
// Correlation pyramid lookup (factorized: dot(fvec, pooled-feature column))
// grid: (B*HW, 8)  block: 64.  blockIdx.y = dir*4 + lvl
// ---------------------------------------------------------------------------
__global__ void lookup_k(const float* __restrict__ f0cl, const float* __restrict__ f1cl,
                         const float* __restrict__ f0p1, const float* __restrict__ f0p2,
                         const float* __restrict__ f0p3,
                         const float* __restrict__ f1p1, const float* __restrict__ f1p2,
                         const float* __restrict__ f1p3,
                         const float* __restrict__ flow0, const float* __restrict__ flow1,
                         const float* __restrict__ embt, float* __restrict__ corr_feat) {
    int bn = blockIdx.x;
    int b  = bn / HWN;
    int n  = bn % HWN;
    int y  = n / WW, x = n % WW;
    int dl = blockIdx.y;
    int dir = dl >> 2, lvl = dl & 3;
    int t  = threadIdx.x;

    __shared__ __align__(16) float fvec[CC];
    __shared__ float dsh[64];

    const float* fsrc = (dir == 0) ? f0cl : f1cl;
    fvec[t]      = fsrc[(size_t)bn * CC + t];
    fvec[t + 64] = fsrc[(size_t)bn * CC + t + 64];

    float e  = embt[b];
    float sc = (dir == 0) ? (1.0f / e) : (1.0f / (1.0f - e));
    const float* fl = (dir == 0) ? flow1 : flow0;
    float fx = fl[((size_t)(b * 2 + 0) * HH + y) * WW + x];
    float fy = fl[((size_t)(b * 2 + 1) * HH + y) * WW + x];
    float cenx = (float)x + fx * sc;
    float ceny = (float)y + fy * sc;
    float inv  = 1.0f / (float)(1 << lvl);
    float cx = cenx * inv, cy = ceny * inv;
    float fx0 = floorf(cx), fy0 = floorf(cy);
    float wx = cx - fx0, wy = cy - fy0;
    int ix0 = (int)fx0, iy0 = (int)fy0;

    const float* map;
    int Hl, Wl;
    if (dir == 0) map = (lvl == 0) ? f1cl : (lvl == 1) ? f1p1 : (lvl == 2) ? f1p2 : f1p3;
    else          map = (lvl == 0) ? f0cl : (lvl == 1) ? f0p1 : (lvl == 2) ? f0p2 : f0p3;
    Hl = (lvl == 0) ? 60 : (lvl == 1) ? 30 : (lvl == 2) ? 15 : 7;
    Wl = (lvl == 0) ? 108 : (lvl == 1) ? 54 : (lvl == 2) ? 27 : 13;

    int rc = t >> 3, ccn = t & 7;
    int xi = ix0 - 3 + ccn;
    int yi = iy0 - 3 + rc;

    __syncthreads();

    float d = 0.0f;
    if ((unsigned)xi < (unsigned)Wl && (unsigned)yi < (unsigned)Hl) {
        const float4* c4 = (const float4*)(map + (((size_t)b * Hl + yi) * Wl + xi) * CC);
        const float4* f4 = (const float4*)fvec;
        float acc = 0.0f;
        #pragma unroll
        for (int i = 0; i < CC / 4; i++) {
            float4 a = f4[i], v = c4[i];
            acc += a.x * v.x + a.y * v.y + a.z * v.z + a.w * v.w;
        }
        d = acc * 0.08838834764831845f;   // 1/sqrt(128)
    }
    dsh[t] = d;
    __syncthreads();

    if (t < 49) {
        int r0 = t / 7, c0 = t % 7;
        float d00 = dsh[r0 * 8 + c0],       d01 = dsh[r0 * 8 + c0 + 1];
        float d10 = dsh[(r0 + 1) * 8 + c0], d11 = dsh[(r0 + 1) * 8 + c0 + 1];
        float val = d00 * (1.0f - wx) * (1.0f - wy) + d01 * wx * (1.0f - wy)
                  + d10 * (1.0f - wx) * wy          + d11 * wx * wy;
        int ch = dir * 196 + lvl * 49 + t;
        corr_feat[((size_t)b * 392 + ch) * HWN + n] = val;
    }
}

// ---------------------------------------------------------------------------
// 1x1 conv (corr encoder): in [B][Cin][HW] -> out channels [ocOff..) of
// [B][outC][HW], ReLU.   block 64, grid (ceil(HW/64), OC/TOC, B)
// ---------------------------------------------------------------------------
template<int TOC>
__global__ void conv1x1_k(const float* __restrict__ in, int Cin,
                          const float* __restrict__ w, const float* __restrict__ bias,
                          float* __restrict__ out, int outC, int ocOff) {
    int n = blockIdx.x * 64 + threadIdx.x;
    if (n >= HWN) return;
    int oc0 = blockIdx.y * TOC;
    int b   = blockIdx.z;
    float acc[TOC];
    #pragma unroll
    for (int j = 0; j < TOC; j++) acc[j] = bias[oc0 + j];
    const float* ip = in + (size_t)b * Cin * HWN + n;
    for (int ic = 0; ic < Cin; ic++) {
        float v = ip[(size_t)ic * HWN];
        #pragma unroll
        for (int j = 0; j < TOC; j++) acc[j] += w[(size_t)(oc0 + j) * Cin + ic] * v;
    }
    #pragma unroll
    for (int j = 0; j < TOC; j++) {
        float a = fmaxf(acc[j], 0.0f);  // ReLU
        out[((size_t)b * outC + ocOff + oc0 + j) * HWN + n] = a;
    }
}

// ---------------------------------------------------------------------------
// Generic 3x3 conv, pad 1, input = concat(inA[CA], inB[CB]), weights from up
// to two arrays (oc < OC1 -> w1, else w2), activation ACT.
// ACT: 0 none, 1 relu, 2 sigmoid, 3 tanh
// block 64 (x), grid (xtiles, H, B*OCG)
// ---------------------------------------------------------------------------
template<int ACT, int TOC>
__global__ void conv3x3_k(const float* __restrict__ inA, int CA,
                          const float* __restrict__ inB, int CB,
                          const float* __restrict__ w1, const float* __restrict__ b1, int OC1,
                          const float* __restrict__ w2, const float* __restrict__ b2, int OC2,
                          float* __restrict__ out, int outC, int ocOff) {
    int x  = blockIdx.x * 64 + threadIdx.x;
    int y  = blockIdx.y;
    int OCtot = OC1 + OC2;
    int OCG = (OCtot + TOC - 1) / TOC;
    int b   = blockIdx.z / OCG;
    int ocg = blockIdx.z % OCG;
    if (x >= WW) return;
    int Ctot = CA + CB;
    int oc0  = ocg * TOC;
    int tn   = OCtot - oc0; if (tn > TOC) tn = TOC;

    const float* wp[TOC];
    float acc[TOC];
    #pragma unroll
    for (int j = 0; j < TOC; j++) {
        int oc = oc0 + j;
        if (j < tn) {
            if (oc < OC1) { wp[j] = w1 + (size_t)oc * Ctot * 9;          acc[j] = b1[oc]; }
            else          { wp[j] = w2 + (size_t)(oc - OC1) * Ctot * 9;  acc[j] = b2[oc - OC1]; }
        } else { wp[j] = w1; acc[j] = 0.0f; }
    }

    for (int ic = 0; ic < Ctot; ic++) {
        const float* plane = (ic < CA)
            ? inA + ((size_t)b * CA + ic) * HWN
            : inB + ((size_t)b * CB + (ic - CA)) * HWN;
        float v[9];
        #pragma unroll
        for (int dy = -1; dy <= 1; dy++) {
            int yy = y + dy;
            bool yv = (unsigned)yy < (unsigned)HH;
            #pragma unroll
            for (int dx = -1; dx <= 1; dx++) {
                int xx = x + dx;
                bool xv = (unsigned)xx < (unsigned)WW;
                v[(dy + 1) * 3 + dx + 1] = (yv && xv) ? plane[(size_t)yy * WW + xx] : 0.0f;
            }
        }
        #pragma unroll
        for (int tap = 0; tap < 9; tap++) {
            float vv = v[tap];
            #pragma unroll
            for (int j = 0; j < TOC; j++) acc[j] += wp[j][ic * 9 + tap] * vv;
        }
    }

    #pragma unroll
    for (int j = 0; j < TOC; j++) {
        if (j < tn) {
            float a = acc[j];
            if (ACT == 1) a = fmaxf(a, 0.0f);
            else if (ACT == 2) a = 1.0f / (1.0f + expf(-a));
            else if (ACT == 3) a = tanhf(a);
            out[((size_t)b * outC + ocOff + oc0 + j) * HWN + (size_t)y * WW + x] = a;
        }
    }
}

// ---------------------------------------------------------------------------
// Elementwise: rh = r * h     (r = zr channels [192..384))
// ---------------------------------------------------------------------------
__global__ void rh_k(const float* __restrict__ zr, const float* __restrict__ h,
                     float* __restrict__ rh) {
    size_t i = (size_t)blockIdx.x * 256 + threadIdx.x;
    const size_t per_b = (size_t)192 * HWN;
    if (i >= (size_t)BB * per_b) return;
    size_t b = i / per_b, off = i % per_b;
    float r = zr[(b * 384 + 192) * HWN + off];
    rh[i] = r * h[i];
}

// ---------------------------------------------------------------------------
// Elementwise: h' = (1-z)*h + z*q   (z = zr channels [0..192))
// ---------------------------------------------------------------------------
__global__ void hnew_k(const float* __restrict__ zr, const float* __restrict__ h,
                       const float* __restrict__ q, float* __restrict__ hn) {
    size_t i = (size_t)blockIdx.x * 256 + threadIdx.x;
    const size_t per_b = (size_t)192 * HWN;
    if (i >= (size_t)BB * per_b) return;
    size_t b = i / per_b, off = i % per_b;
    float z = zr[b * 384 * HWN + off];
    hn[i] = (1.0f - z) * h[i] + z * q[i];
}

// ---------------------------------------------------------------------------
extern "C" void kernel_launch(void* const* d_in, const int* in_sizes, int n_in,
                              void* d_out, int out_size, void* d_ws, size_t ws_size,
                              hipStream_t stream) {
    const float* fmap0 = (const float*)d_in[0];
    const float* fmap1 = (const float*)d_in[1];
    const float* ft    = (const float*)d_in[2];
    const float* flow0 = (const float*)d_in[3];
    const float* flow1 = (const float*)d_in[4];
    const float* embt  = (const float*)d_in[5];
    const float* w_corr = (const float*)d_in[6];
    const float* b_corr = (const float*)d_in[7];
    const float* w_flow = (const float*)d_in[8];
    const float* b_flow = (const float*)d_in[9];
    const float* w_ctx  = (const float*)d_in[10];
    const float* b_ctx  = (const float*)d_in[11];
    const float* w_z    = (const float*)d_in[12];
    const float* b_z    = (const float*)d_in[13];
    const float* w_r    = (const float*)d_in[14];
    const float* b_r    = (const float*)d_in[15];
    const float* w_q    = (const float*)d_in[16];
    const float* b_q    = (const float*)d_in[17];
    const float* w_fh   = (const float*)d_in[18];
    const float* b_fh   = (const float*)d_in[19];
    const float* w_dh   = (const float*)d_in[20];
    const float* b_dh   = (const float*)d_in[21];
    float* out = (float*)d_out;

    char* ws = (char*)d_ws;
    size_t off = 0;
    auto alloc = [&](size_t bytes) { size_t o = off; off += (bytes + 255) & ~(size_t)255; return o; };

    // channel-last pooled feature maps
    float* f0cl = (float*)(ws + alloc((size_t)BB * HWN * CC * 4));
    float* f1cl = (float*)(ws + alloc((size_t)BB * HWN * CC * 4));
    float* f0p1 = (float*)(ws + alloc((size_t)BB * 30 * 54 * CC * 4));
    float* f0p2 = (float*)(ws + alloc((size_t)BB * 15 * 27 * CC * 4));
    float* f0p3 = (float*)(ws + alloc((size_t)BB * 7 * 13 * CC * 4));
    float* f1p1 = (float*)(ws + alloc((size_t)BB * 30 * 54 * CC * 4));
    float* f1p2 = (float*)(ws + alloc((size_t)BB * 15 * 27 * CC * 4));
    float* f1p3 = (float*)(ws + alloc((size_t)BB * 7 * 13 * CC * 4));
    // activations
    float* corr_feat = (float*)(ws + alloc((size_t)BB * 392 * HWN * 4)); // aliased as zr later
    float* inp  = (float*)(ws + alloc((size_t)BB * 320 * HWN * 4));
    float* hbuf = (float*)(ws + alloc((size_t)BB * 192 * HWN * 4));
    float* rhbuf= (float*)(ws + alloc((size_t)BB * 192 * HWN * 4)); // also reused for h'
    float* qbuf = (float*)(ws + alloc((size_t)BB * 192 * HWN * 4));
    float* zrbuf = corr_feat;  // 384 <= 392 channels; corr_feat dead after conv1x1

    // 1) channel-last transpose of fmap0/fmap1
    transpose_cl_k<<<dim3(BB * HWN), dim3(128), 0, stream>>>(fmap0, f0cl);
    transpose_cl_k<<<dim3(BB * HWN), dim3(128), 0, stream>>>(fmap1, f1cl);

    // 2) pooled pyramids (2x2 avg, VALID)
    pool_k<<<dim3(BB * 30 * 54), dim3(128), 0, stream>>>(f0cl, f0p1, 60, 108, 30, 54);
    pool_k<<<dim3(BB * 15 * 27), dim3(128), 0, stream>>>(f0p1, f0p2, 30, 54, 15, 27);
    pool_k<<<dim3(BB * 7 * 13),  dim3(128), 0, stream>>>(f0p2, f0p3, 15, 27, 7, 13);
    pool_k<<<dim3(BB * 30 * 54), dim3(128), 0, stream>>>(f1cl, f1p1, 60, 108, 30, 54);
    pool_k<<<dim3(BB * 15 * 27), dim3(128), 0, stream>>>(f1p1, f1p2, 30, 54, 15, 27);
    pool_k<<<dim3(BB * 7 * 13),  dim3(128), 0, stream>>>(f1p2, f1p3, 15, 27, 7, 13);

    // 3) bidirectional pyramid lookup -> corr_feat [B][392][HW]
    lookup_k<<<dim3(BB * HWN, 8), dim3(64), 0, stream>>>(
        f0cl, f1cl, f0p1, f0p2, f0p3, f1p1, f1p2, f1p3,
        flow0, flow1, embt, corr_feat);

    // 4) motion encoder: cfeat = relu(1x1 conv) -> inp[0:256)
    conv1x1_k<8><<<dim3((HWN + 63) / 64, 256 / 8, BB), dim3(64), 0, stream>>>(
        corr_feat, 392, w_corr, b_corr, inp, 320, 0);

    // 5) ffeat = relu(3x3 conv concat(flow0,flow1)) -> inp[256:320)
    conv3x3_k<1, 8><<<dim3(2, HH, BB * (64 / 8)), dim3(64), 0, stream>>>(
        flow0, 2, flow1, 2, w_flow, b_flow, 64, w_flow, b_flow, 0, inp, 320, 256);

    // 6) h = tanh(3x3 conv ft)
    conv3x3_k<3, 8><<<dim3(2, HH, BB * (192 / 8)), dim3(64), 0, stream>>>(
        ft, 112, ft, 0, w_ctx, b_ctx, 192, w_ctx, b_ctx, 0, hbuf, 192, 0);

    // 7) z,r = sigmoid(3x3 conv concat(h, inp))  -> zrbuf [B][384][HW]
    conv3x3_k<2, 8><<<dim3(2, HH, BB * (384 / 8)), dim3(64), 0, stream>>>(
        hbuf, 192, inp, 320, w_z, b_z, 192, w_r, b_r, 192, zrbuf, 384, 0);

    // 8) rh = r * h
    {
        size_t total = (size_t)BB * 192 * HWN;
        rh_k<<<dim3((unsigned)((total + 255) / 256)), dim3(256), 0, stream>>>(zrbuf, hbuf, rhbuf);
    }

    // 9) q = tanh(3x3 conv concat(rh, inp))
    conv3x3_k<3, 8><<<dim3(2, HH, BB * (192 / 8)), dim3(64), 0, stream>>>(
        rhbuf, 192, inp, 320, w_q, b_q, 192, w_q, b_q, 0, qbuf, 192, 0);

    // 10) h' = (1-z)h + z*q   (into rhbuf, rh dead now)
    {
        size_t total = (size_t)BB * 192 * HWN;
        hnew_k<<<dim3((unsigned)((total + 255) / 256)), dim3(256), 0, stream>>>(zrbuf, hbuf, qbuf, rhbuf);
    }

    // 11) output: [delta_ft(112, w_dh); delta_flow(4, w_fh)] -> d_out [B][116][HW]
    conv3x3_k<0, 8><<<dim3(2, HH, BB * ((116 + 7) / 8)), dim3(64), 0, stream>>>(
        rhbuf, 192, rhbuf, 0, w_dh, b_dh, 112, w_fh, b_fh, 4, out, 116, 0);
}

// Round 5
// 814.977 us; speedup vs baseline: 4.8357x; 4.8357x over previous
//
#include <hip/hip_runtime.h>
#include <hip/hip_bf16.h>
#include <math.h>

#define BB 2
#define CC 128
#define HH 60
#define WW 108
#define HWN (HH*WW)

typedef __attribute__((ext_vector_type(8))) short s16x8;
typedef __attribute__((ext_vector_type(4))) float f32x4;

__device__ __forceinline__ unsigned short f2b(float f) {
    union { float f; unsigned int u; } v; v.f = f;
    unsigned int r = (v.u + 0x7FFFu + ((v.u >> 16) & 1u)) >> 16;
    return (unsigned short)r;
}
__device__ __forceinline__ float b2f(unsigned short b) {
    union { unsigned int u; float f; } v; v.u = ((unsigned int)b) << 16;
    return v.f;
}

// ---------------------------------------------------------------------------
// fmap [B][128][HW] f32 -> [B][HW][128] f32 (channel-last, for lookup)
// ---------------------------------------------------------------------------
__global__ void f2cl_k(const float* __restrict__ in, float* __restrict__ out) {
    int n = blockIdx.x * 64 + threadIdx.x;
    int b = blockIdx.y;
    if (n >= HWN) return;
    const float* ip = in + (size_t)b * CC * HWN + n;
    float* op = out + ((size_t)b * HWN + n) * CC;
    for (int c0 = 0; c0 < CC; c0 += 4) {
        float4 o;
        o.x = ip[(size_t)(c0 + 0) * HWN];
        o.y = ip[(size_t)(c0 + 1) * HWN];
        o.z = ip[(size_t)(c0 + 2) * HWN];
        o.w = ip[(size_t)(c0 + 3) * HWN];
        *(float4*)(op + c0) = o;
    }
}

// ---------------------------------------------------------------------------
// ft [B][112][HW] f32 -> [B][HW][128] bf16 (pad 112..127 zero)
// ---------------------------------------------------------------------------
__global__ void ft2cl_k(const float* __restrict__ ft, unsigned short* __restrict__ out) {
    int n = blockIdx.x * 64 + threadIdx.x;
    int b = blockIdx.y;
    if (n >= HWN) return;
    const float* ip = ft + (size_t)b * 112 * HWN + n;
    unsigned short* op = out + ((size_t)b * HWN + n) * 128;
    for (int c0 = 0; c0 < 112; c0 += 8) {
        s16x8 o;
        #pragma unroll
        for (int j = 0; j < 8; j++) o[j] = (short)f2b(ip[(size_t)(c0 + j) * HWN]);
        *(s16x8*)(op + c0) = o;
    }
    s16x8 z = {};
    *(s16x8*)(op + 112) = z;
    *(s16x8*)(op + 120) = z;
}

// ---------------------------------------------------------------------------
// 2x2 avg pool on channel-last f32 maps
// ---------------------------------------------------------------------------
__global__ void pool_k(const float* __restrict__ in, float* __restrict__ out,
                       int Hi, int Wi, int Ho, int Wo) {
    int bp = blockIdx.x;
    int b  = bp / (Ho * Wo);
    int p  = bp % (Ho * Wo);
    int yo = p / Wo, xo = p % Wo;
    int c  = threadIdx.x;
    const float* i0 = in + (((size_t)b * Hi + 2 * yo) * Wi + 2 * xo) * CC;
    float v = i0[c] + i0[CC + c] + i0[(size_t)Wi * CC + c] + i0[(size_t)Wi * CC + CC + c];
    out[(((size_t)b * Ho + yo) * Wo + xo) * CC + c] = 0.25f * v;
}

// ---------------------------------------------------------------------------
// Correlation pyramid lookup -> corr_cl [B][HW][416] bf16 (ch 392..415 unused)
// grid: (B*HW, 8) block 64. blockIdx.y = dir*4+lvl
// ---------------------------------------------------------------------------
__global__ void lookup_k(const float* __restrict__ f0cl, const float* __restrict__ f1cl,
                         const float* __restrict__ f0p1, const float* __restrict__ f0p2,
                         const float* __restrict__ f0p3,
                         const float* __restrict__ f1p1, const float* __restrict__ f1p2,
                         const float* __restrict__ f1p3,
                         const float* __restrict__ flow0, const float* __restrict__ flow1,
                         const float* __restrict__ embt, unsigned short* __restrict__ corr_cl) {
    int bn = blockIdx.x;
    int b  = bn / HWN;
    int n  = bn % HWN;
    int y  = n / WW, x = n % WW;
    int dl = blockIdx.y;
    int dir = dl >> 2, lvl = dl & 3;
    int t  = threadIdx.x;

    __shared__ __align__(16) float fvec[CC];
    __shared__ float dsh[64];

    const float* fsrc = (dir == 0) ? f0cl : f1cl;
    fvec[t]      = fsrc[(size_t)bn * CC + t];
    fvec[t + 64] = fsrc[(size_t)bn * CC + t + 64];

    float e  = embt[b];
    float sc = (dir == 0) ? (1.0f / e) : (1.0f / (1.0f - e));
    const float* fl = (dir == 0) ? flow1 : flow0;
    float fx = fl[((size_t)(b * 2 + 0) * HH + y) * WW + x];
    float fy = fl[((size_t)(b * 2 + 1) * HH + y) * WW + x];
    float inv = 1.0f / (float)(1 << lvl);
    float cx = ((float)x + fx * sc) * inv;
    float cy = ((float)y + fy * sc) * inv;
    float fx0 = floorf(cx), fy0 = floorf(cy);
    float wx = cx - fx0, wy = cy - fy0;
    int ix0 = (int)fx0, iy0 = (int)fy0;

    const float* map;
    if (dir == 0) map = (lvl == 0) ? f1cl : (lvl == 1) ? f1p1 : (lvl == 2) ? f1p2 : f1p3;
    else          map = (lvl == 0) ? f0cl : (lvl == 1) ? f0p1 : (lvl == 2) ? f0p2 : f0p3;
    int Hl = (lvl == 0) ? 60 : (lvl == 1) ? 30 : (lvl == 2) ? 15 : 7;
    int Wl = (lvl == 0) ? 108 : (lvl == 1) ? 54 : (lvl == 2) ? 27 : 13;

    int rc = t >> 3, ccn = t & 7;
    int xi = ix0 - 3 + ccn;
    int yi = iy0 - 3 + rc;

    __syncthreads();

    float d = 0.0f;
    if ((unsigned)xi < (unsigned)Wl && (unsigned)yi < (unsigned)Hl) {
        const float4* c4 = (const float4*)(map + (((size_t)b * Hl + yi) * Wl + xi) * CC);
        const float4* f4 = (const float4*)fvec;
        float acc = 0.0f;
        #pragma unroll
        for (int i = 0; i < CC / 4; i++) {
            float4 a = f4[i], v = c4[i];
            acc += a.x * v.x + a.y * v.y + a.z * v.z + a.w * v.w;
        }
        d = acc * 0.08838834764831845f;  // 1/sqrt(128)
    }
    dsh[t] = d;
    __syncthreads();

    if (t < 49) {
        int r0 = t / 7, c0 = t % 7;
        float d00 = dsh[r0 * 8 + c0],       d01 = dsh[r0 * 8 + c0 + 1];
        float d10 = dsh[(r0 + 1) * 8 + c0], d11 = dsh[(r0 + 1) * 8 + c0 + 1];
        float val = d00 * (1.0f - wx) * (1.0f - wy) + d01 * wx * (1.0f - wy)
                  + d10 * (1.0f - wx) * wy          + d11 * wx * wy;
        int ch = dir * 196 + lvl * 49 + t;
        corr_cl[(size_t)bn * 416 + ch] = f2b(val);
    }
}

// ---------------------------------------------------------------------------
// Pack conv weights (f32 OIHW, optional concat w1|w2 along O, zero-pad O and I)
// into MFMA B-fragment layout: chunk idx = ((tap*KSTEPS+ks)*TOTOCT+oct)*64+lane,
// 8 bf16 per chunk: oc = oct*16+(lane&15), k = ks*32+(lane>>4)*8+j, ic = k.
// ---------------------------------------------------------------------------
__global__ void packw_k(const float* __restrict__ w1, const float* __restrict__ w2,
                        int OC1, int OCreal, int Cin, int TAPS, int KSTEPS, int TOTOCT,
                        unsigned short* __restrict__ out) {
    int idx = blockIdx.x * 256 + threadIdx.x;
    int total = TAPS * KSTEPS * TOTOCT * 64;
    if (idx >= total) return;
    int lane = idx & 63;
    int rest = idx >> 6;
    int oct  = rest % TOTOCT;
    int rk   = rest / TOTOCT;
    int ks   = rk % KSTEPS;
    int tap  = rk / KSTEPS;
    int oc = oct * 16 + (lane & 15);
    int kb = ks * 32 + (lane >> 4) * 8;
    s16x8 o;
    #pragma unroll
    for (int j = 0; j < 8; j++) {
        int ic = kb + j;
        float val = 0.0f;
        if (oc < OCreal && ic < Cin) {
            val = (oc < OC1) ? w1[((size_t)oc * Cin + ic) * TAPS + tap]
                             : w2[((size_t)(oc - OC1) * Cin + ic) * TAPS + tap];
        }
        o[j] = (short)f2b(val);
    }
    *(s16x8*)(out + (size_t)idx * 8) = o;
}

// ---------------------------------------------------------------------------
// MFMA implicit-GEMM conv. M=pixels, N=oc.  A[i][k]: i=lane&15 (pixel),
// k=8*(lane>>4)+j. B from packed weights. D: col(oc)=lane&15, row(pixel)=
// 4*(lane>>4)+reg. Block 256 (4 waves, each 16 pixels). grid (102, OCG, B).
// ACT: 0 none 1 relu 2 sigmoid 3 tanh. EPI: 0 bf16 CL, 1 bf16 CL x2, 2 f32 CF.
// ---------------------------------------------------------------------------
template<int NOCT, int TAPS, int ACT, int EPI>
__launch_bounds__(256)
__global__ void convmf_k(const unsigned short* __restrict__ gin, int CS, int KSTEPS,
                         const unsigned short* __restrict__ wp,
                         const float* __restrict__ bias1, const float* __restrict__ bias2,
                         int OC1, int OCreal,
                         unsigned short* __restrict__ gout, int OCS, int ocoff,
                         unsigned short* __restrict__ gout2, int OCS2,
                         float* __restrict__ fout) {
    int lane = threadIdx.x & 63;
    int wv   = threadIdx.x >> 6;
    int pt   = blockIdx.x;
    int ocg  = blockIdx.y;
    int b    = blockIdx.z;
    int TOTOCT = gridDim.y * NOCT;
    int p0 = pt * 64 + wv * 16;
    int pa = p0 + (lane & 15);
    bool pv = pa < HWN;
    int py = pa / WW, px = pa - py * WW;
    const unsigned short* abase = gin + ((size_t)b * HWN + pa) * CS + (lane >> 4) * 8;
    int oct0 = ocg * NOCT;

    f32x4 acc[NOCT];
    #pragma unroll
    for (int t = 0; t < NOCT; t++) acc[t] = f32x4{0.f, 0.f, 0.f, 0.f};

    for (int tap = 0; tap < TAPS; tap++) {
        int dy = (TAPS == 1) ? 0 : (tap / 3 - 1);
        int dx = (TAPS == 1) ? 0 : (tap % 3 - 1);
        bool v = pv && ((unsigned)(py + dy) < (unsigned)HH) && ((unsigned)(px + dx) < (unsigned)WW);
        const unsigned short* ap = abase + (dy * WW + dx) * CS;
        const unsigned short* bp = wp + ((size_t)(tap * KSTEPS) * TOTOCT + oct0) * 512 + (size_t)lane * 8;
        for (int ks = 0; ks < KSTEPS; ks++) {
            s16x8 a = {};
            if (v) a = *(const s16x8*)(ap + ks * 32);
            const unsigned short* bpp = bp + (size_t)ks * TOTOCT * 512;
            #pragma unroll
            for (int t = 0; t < NOCT; t++) {
                s16x8 bf = *(const s16x8*)(bpp + (size_t)t * 512);
                acc[t] = __builtin_amdgcn_mfma_f32_16x16x32_bf16(a, bf, acc[t], 0, 0, 0);
            }
        }
    }

    int oc_l = lane & 15;
    int prow = p0 + (lane >> 4) * 4;
    #pragma unroll
    for (int t = 0; t < NOCT; t++) {
        int oc = (oct0 + t) * 16 + oc_l;
        float bs = 0.0f;
        if (oc < OCreal) bs = (oc < OC1) ? bias1[oc] : bias2[oc - OC1];
        #pragma unroll
        for (int r = 0; r < 4; r++) {
            int p = prow + r;
            if (p >= HWN) continue;
            float vv = acc[t][r] + bs;
            if (ACT == 1) vv = fmaxf(vv, 0.0f);
            else if (ACT == 2) vv = 1.0f / (1.0f + __expf(-vv));
            else if (ACT == 3) vv = tanhf(vv);
            if (EPI == 2) {
                if (oc < OCreal) fout[((size_t)b * OCreal + oc) * HWN + p] = vv;
            } else {
                unsigned short bvv = f2b(vv);
                gout[((size_t)b * HWN + p) * OCS + ocoff + oc] = bvv;
                if (EPI == 1) gout2[((size_t)b * HWN + p) * OCS2 + oc] = bvv;
            }
        }
    }
}

// ---------------------------------------------------------------------------
// flow conv (4->64, 3x3, relu), direct f32, writes gi ch 448..511 bf16
// ---------------------------------------------------------------------------
__global__ void flowconv_k(const float* __restrict__ flow0, const float* __restrict__ flow1,
                           const float* __restrict__ w, const float* __restrict__ bias,
                           unsigned short* __restrict__ gi) {
    int n = blockIdx.x * 64 + threadIdx.x;
    int b = blockIdx.y;
    if (n >= HWN) return;
    int y = n / WW, x = n - y * WW;
    float v[36];
    for (int c = 0; c < 4; c++) {
        const float* pl = (c < 2) ? flow0 + ((size_t)b * 2 + c) * HWN
                                  : flow1 + ((size_t)b * 2 + (c - 2)) * HWN;
        #pragma unroll
        for (int dy = -1; dy <= 1; dy++)
            #pragma unroll
            for (int dx = -1; dx <= 1; dx++) {
                int yy = y + dy, xx = x + dx;
                v[c * 9 + (dy + 1) * 3 + (dx + 1)] =
                    (((unsigned)yy < (unsigned)HH) && ((unsigned)xx < (unsigned)WW))
                        ? pl[(size_t)yy * WW + xx] : 0.0f;
            }
    }
    unsigned short* op = gi + ((size_t)b * HWN + n) * 512 + 448;
    for (int oc0 = 0; oc0 < 64; oc0 += 8) {
        s16x8 o;
        #pragma unroll
        for (int j = 0; j < 8; j++) {
            int oc = oc0 + j;
            const float* wpp = w + (size_t)oc * 36;
            float a = bias[oc];
            #pragma unroll
            for (int k = 0; k < 36; k++) a += wpp[k] * v[k];
            o[j] = (short)f2b(fmaxf(a, 0.0f));
        }
        *(s16x8*)(op + oc0) = o;
    }
}

// ---------------------------------------------------------------------------
// rh: gi[ch 0..191] = r * h   (r = sigmoid'd, zr ch192..383; h from hsep)
// ---------------------------------------------------------------------------
__global__ void rh_k(const unsigned short* __restrict__ zr, const unsigned short* __restrict__ hs,
                     unsigned short* __restrict__ gi) {
    int idx = blockIdx.x * 256 + threadIdx.x;
    if (idx >= BB * HWN * 24) return;
    int n = idx / 24, c8 = (idx % 24) * 8;
    s16x8 r = *(const s16x8*)(zr + (size_t)n * 384 + 192 + c8);
    s16x8 h = *(const s16x8*)(hs + (size_t)n * 192 + c8);
    s16x8 o;
    #pragma unroll
    for (int j = 0; j < 8; j++)
        o[j] = (short)f2b(b2f((unsigned short)r[j]) * b2f((unsigned short)h[j]));
    *(s16x8*)(gi + (size_t)n * 512 + c8) = o;
}

// ---------------------------------------------------------------------------
// hnew: gi[ch 0..191] = (1-z)*h + z*q
// ---------------------------------------------------------------------------
__global__ void hnew_k(const unsigned short* __restrict__ zr, const unsigned short* __restrict__ hs,
                       const unsigned short* __restrict__ q, unsigned short* __restrict__ gi) {
    int idx = blockIdx.x * 256 + threadIdx.x;
    if (idx >= BB * HWN * 24) return;
    int n = idx / 24, c8 = (idx % 24) * 8;
    s16x8 z = *(const s16x8*)(zr + (size_t)n * 384 + c8);
    s16x8 h = *(const s16x8*)(hs + (size_t)n * 192 + c8);
    s16x8 qq = *(const s16x8*)(q + (size_t)n * 192 + c8);
    s16x8 o;
    #pragma unroll
    for (int j = 0; j < 8; j++) {
        float zf = b2f((unsigned short)z[j]);
        o[j] = (short)f2b((1.0f - zf) * b2f((unsigned short)h[j]) + zf * b2f((unsigned short)qq[j]));
    }
    *(s16x8*)(gi + (size_t)n * 512 + c8) = o;
}

// ---------------------------------------------------------------------------
extern "C" void kernel_launch(void* const* d_in, const int* in_sizes, int n_in,
                              void* d_out, int out_size, void* d_ws, size_t ws_size,
                              hipStream_t stream) {
    const float* fmap0 = (const float*)d_in[0];
    const float* fmap1 = (const float*)d_in[1];
    const float* ft    = (const float*)d_in[2];
    const float* flow0 = (const float*)d_in[3];
    const float* flow1 = (const float*)d_in[4];
    const float* embt  = (const float*)d_in[5];
    const float* w_corr = (const float*)d_in[6];
    const float* b_corr = (const float*)d_in[7];
    const float* w_flow = (const float*)d_in[8];
    const float* b_flow = (const float*)d_in[9];
    const float* w_ctx  = (const float*)d_in[10];
    const float* b_ctx  = (const float*)d_in[11];
    const float* w_z    = (const float*)d_in[12];
    const float* b_z    = (const float*)d_in[13];
    const float* w_r    = (const float*)d_in[14];
    const float* b_r    = (const float*)d_in[15];
    const float* w_q    = (const float*)d_in[16];
    const float* b_q    = (const float*)d_in[17];
    const float* w_fh   = (const float*)d_in[18];
    const float* b_fh   = (const float*)d_in[19];
    const float* w_dh   = (const float*)d_in[20];
    const float* b_dh   = (const float*)d_in[21];
    float* out = (float*)d_out;

    char* ws = (char*)d_ws;
    size_t off = 0;
    auto alloc = [&](size_t bytes) { size_t o = off; off += (bytes + 255) & ~(size_t)255; return o; };

    float* f0cl = (float*)(ws + alloc((size_t)BB * HWN * CC * 4));
    float* f1cl = (float*)(ws + alloc((size_t)BB * HWN * CC * 4));
    float* f0p1 = (float*)(ws + alloc((size_t)BB * 30 * 54 * CC * 4));
    float* f0p2 = (float*)(ws + alloc((size_t)BB * 15 * 27 * CC * 4));
    float* f0p3 = (float*)(ws + alloc((size_t)BB * 7 * 13 * CC * 4));
    float* f1p1 = (float*)(ws + alloc((size_t)BB * 30 * 54 * CC * 4));
    float* f1p2 = (float*)(ws + alloc((size_t)BB * 15 * 27 * CC * 4));
    float* f1p3 = (float*)(ws + alloc((size_t)BB * 7 * 13 * CC * 4));
    unsigned short* ftcl   = (unsigned short*)(ws + alloc((size_t)BB * HWN * 128 * 2));
    unsigned short* corrcl = (unsigned short*)(ws + alloc((size_t)BB * HWN * 416 * 2));
    unsigned short* gi     = (unsigned short*)(ws + alloc((size_t)BB * HWN * 512 * 2));
    unsigned short* hsep   = (unsigned short*)(ws + alloc((size_t)BB * HWN * 192 * 2));
    unsigned short* zrbuf  = (unsigned short*)(ws + alloc((size_t)BB * HWN * 384 * 2));
    unsigned short* qbuf   = (unsigned short*)(ws + alloc((size_t)BB * HWN * 192 * 2));
    unsigned short* wpzr   = (unsigned short*)(ws + alloc((size_t)9 * 16 * 24 * 64 * 8 * 2));
    unsigned short* wpq    = (unsigned short*)(ws + alloc((size_t)9 * 16 * 12 * 64 * 8 * 2));
    unsigned short* wpctx  = (unsigned short*)(ws + alloc((size_t)9 * 4 * 12 * 64 * 8 * 2));
    unsigned short* wpdh   = (unsigned short*)(ws + alloc((size_t)9 * 6 * 8 * 64 * 8 * 2));
    unsigned short* wpcorr = (unsigned short*)(ws + alloc((size_t)1 * 13 * 16 * 64 * 8 * 2));

    // weight packing
    packw_k<<<dim3((9 * 16 * 24 * 64 + 255) / 256), dim3(256), 0, stream>>>(
        w_z, w_r, 192, 384, 512, 9, 16, 24, wpzr);
    packw_k<<<dim3((9 * 16 * 12 * 64 + 255) / 256), dim3(256), 0, stream>>>(
        w_q, w_q, 192, 192, 512, 9, 16, 12, wpq);
    packw_k<<<dim3((9 * 4 * 12 * 64 + 255) / 256), dim3(256), 0, stream>>>(
        w_ctx, w_ctx, 192, 192, 112, 9, 4, 12, wpctx);
    packw_k<<<dim3((9 * 6 * 8 * 64 + 255) / 256), dim3(256), 0, stream>>>(
        w_dh, w_fh, 112, 116, 192, 9, 6, 8, wpdh);
    packw_k<<<dim3((1 * 13 * 16 * 64 + 255) / 256), dim3(256), 0, stream>>>(
        w_corr, w_corr, 256, 256, 392, 1, 13, 16, wpcorr);

    // channel-last transposes + pyramids
    f2cl_k<<<dim3((HWN + 63) / 64, BB), dim3(64), 0, stream>>>(fmap0, f0cl);
    f2cl_k<<<dim3((HWN + 63) / 64, BB), dim3(64), 0, stream>>>(fmap1, f1cl);
    ft2cl_k<<<dim3((HWN + 63) / 64, BB), dim3(64), 0, stream>>>(ft, ftcl);
    pool_k<<<dim3(BB * 30 * 54), dim3(128), 0, stream>>>(f0cl, f0p1, 60, 108, 30, 54);
    pool_k<<<dim3(BB * 15 * 27), dim3(128), 0, stream>>>(f0p1, f0p2, 30, 54, 15, 27);
    pool_k<<<dim3(BB * 7 * 13),  dim3(128), 0, stream>>>(f0p2, f0p3, 15, 27, 7, 13);
    pool_k<<<dim3(BB * 30 * 54), dim3(128), 0, stream>>>(f1cl, f1p1, 60, 108, 30, 54);
    pool_k<<<dim3(BB * 15 * 27), dim3(128), 0, stream>>>(f1p1, f1p2, 30, 54, 15, 27);
    pool_k<<<dim3(BB * 7 * 13),  dim3(128), 0, stream>>>(f1p2, f1p3, 15, 27, 7, 13);

    // lookup -> corr_cl bf16 [B][HW][416]
    lookup_k<<<dim3(BB * HWN, 8), dim3(64), 0, stream>>>(
        f0cl, f1cl, f0p1, f0p2, f0p3, f1p1, f1p2, f1p3,
        flow0, flow1, embt, corrcl);

    // ffeat -> gi ch 448..511
    flowconv_k<<<dim3((HWN + 63) / 64, BB), dim3(64), 0, stream>>>(flow0, flow1, w_flow, b_flow, gi);

    // cfeat = relu(1x1) -> gi ch 192..447
    convmf_k<4, 1, 1, 0><<<dim3(102, 4, BB), dim3(256), 0, stream>>>(
        corrcl, 416, 13, wpcorr, b_corr, b_corr, 256, 256, gi, 512, 192, nullptr, 0, nullptr);

    // h = tanh(ctx conv) -> gi ch 0..191 AND hsep
    convmf_k<3, 9, 3, 1><<<dim3(102, 4, BB), dim3(256), 0, stream>>>(
        ftcl, 128, 4, wpctx, b_ctx, b_ctx, 192, 192, gi, 512, 0, hsep, 192, nullptr);

    // z|r = sigmoid(conv(gi)) -> zrbuf [B][HW][384]
    convmf_k<6, 9, 2, 0><<<dim3(102, 4, BB), dim3(256), 0, stream>>>(
        gi, 512, 16, wpzr, b_z, b_r, 192, 384, zrbuf, 384, 0, nullptr, 0, nullptr);

    // gi ch0..191 = r*h
    rh_k<<<dim3((BB * HWN * 24 + 255) / 256), dim3(256), 0, stream>>>(zrbuf, hsep, gi);

    // q = tanh(conv(gi)) -> qbuf
    convmf_k<3, 9, 3, 0><<<dim3(102, 4, BB), dim3(256), 0, stream>>>(
        gi, 512, 16, wpq, b_q, b_q, 192, 192, qbuf, 192, 0, nullptr, 0, nullptr);

    // gi ch0..191 = (1-z)h + z q
    hnew_k<<<dim3((BB * HWN * 24 + 255) / 256), dim3(256), 0, stream>>>(zrbuf, hsep, qbuf, gi);

    // out = [dh(112); fh(4)] conv of h' (gi ch0..191, stride 512) -> f32 CF
    convmf_k<2, 9, 0, 2><<<dim3(102, 4, BB), dim3(256), 0, stream>>>(
        gi, 512, 6, wpdh, b_dh, b_fh, 112, 116, nullptr, 0, 0, nullptr, 0, out);
}

// Round 6
// 588.157 us; speedup vs baseline: 6.7005x; 1.3856x over previous
//
#include <hip/hip_runtime.h>
#include <hip/hip_bf16.h>
#include <math.h>

#define BB 2
#define CC 128
#define HH 60
#define WW 108
#define HWN (HH*WW)

typedef __attribute__((ext_vector_type(8))) short s16x8;
typedef __attribute__((ext_vector_type(4))) float f32x4;

__device__ __forceinline__ unsigned short f2b(float f) {
    union { float f; unsigned int u; } v; v.f = f;
    unsigned int r = (v.u + 0x7FFFu + ((v.u >> 16) & 1u)) >> 16;
    return (unsigned short)r;
}
__device__ __forceinline__ float b2f(unsigned short b) {
    union { unsigned int u; float f; } v; v.u = ((unsigned int)b) << 16;
    return v.f;
}

// ---------------------------------------------------------------------------
// fmap [B][128][HW] f32 -> [B][HW][128] f32 (channel-last, for lookup)
// ---------------------------------------------------------------------------
__global__ void f2cl_k(const float* __restrict__ in, float* __restrict__ out) {
    int n = blockIdx.x * 64 + threadIdx.x;
    int b = blockIdx.y;
    if (n >= HWN) return;
    const float* ip = in + (size_t)b * CC * HWN + n;
    float* op = out + ((size_t)b * HWN + n) * CC;
    for (int c0 = 0; c0 < CC; c0 += 4) {
        float4 o;
        o.x = ip[(size_t)(c0 + 0) * HWN];
        o.y = ip[(size_t)(c0 + 1) * HWN];
        o.z = ip[(size_t)(c0 + 2) * HWN];
        o.w = ip[(size_t)(c0 + 3) * HWN];
        *(float4*)(op + c0) = o;
    }
}

// ---------------------------------------------------------------------------
// ft [B][112][HW] f32 -> [B][HW][128] bf16 (pad 112..127 zero)
// ---------------------------------------------------------------------------
__global__ void ft2cl_k(const float* __restrict__ ft, unsigned short* __restrict__ out) {
    int n = blockIdx.x * 64 + threadIdx.x;
    int b = blockIdx.y;
    if (n >= HWN) return;
    const float* ip = ft + (size_t)b * 112 * HWN + n;
    unsigned short* op = out + ((size_t)b * HWN + n) * 128;
    for (int c0 = 0; c0 < 112; c0 += 8) {
        s16x8 o;
        #pragma unroll
        for (int j = 0; j < 8; j++) o[j] = (short)f2b(ip[(size_t)(c0 + j) * HWN]);
        *(s16x8*)(op + c0) = o;
    }
    s16x8 z = {};
    *(s16x8*)(op + 112) = z;
    *(s16x8*)(op + 120) = z;
}

// ---------------------------------------------------------------------------
// 2x2 avg pool on channel-last f32 maps
// ---------------------------------------------------------------------------
__global__ void pool_k(const float* __restrict__ in, float* __restrict__ out,
                       int Hi, int Wi, int Ho, int Wo) {
    int bp = blockIdx.x;
    int b  = bp / (Ho * Wo);
    int p  = bp % (Ho * Wo);
    int yo = p / Wo, xo = p % Wo;
    int c  = threadIdx.x;
    const float* i0 = in + (((size_t)b * Hi + 2 * yo) * Wi + 2 * xo) * CC;
    float v = i0[c] + i0[CC + c] + i0[(size_t)Wi * CC + c] + i0[(size_t)Wi * CC + CC + c];
    out[(((size_t)b * Ho + yo) * Wo + xo) * CC + c] = 0.25f * v;
}

// ---------------------------------------------------------------------------
// Correlation pyramid lookup -> corr_cl [B][HW][416] bf16 (ch 392..415 unused)
// grid: (B*HW, 2) block 256. blockIdx.y = dir; wave (tid>>6) = level.
// Per pass p (=window row): 8 groups of 8 lanes; group g reads column p*8+g
// cooperatively (lane sub reads 16B chunks -> contiguous 128B per group).
// Partial dots reduced with shfl_xor over the 8-lane group.
// ---------------------------------------------------------------------------
__global__ void lookup_k(const float* __restrict__ f0cl, const float* __restrict__ f1cl,
                         const float* __restrict__ f0p1, const float* __restrict__ f0p2,
                         const float* __restrict__ f0p3,
                         const float* __restrict__ f1p1, const float* __restrict__ f1p2,
                         const float* __restrict__ f1p3,
                         const float* __restrict__ flow0, const float* __restrict__ flow1,
                         const float* __restrict__ embt, unsigned short* __restrict__ corr_cl) {
    int bn = blockIdx.x;
    int b  = bn / HWN;
    int n  = bn % HWN;
    int y  = n / WW, x = n % WW;
    int dir = blockIdx.y;
    int tid = threadIdx.x;
    int lane = tid & 63;
    int lvl  = tid >> 6;

    __shared__ __align__(16) float fvec[CC];
    __shared__ float dsh[4][64];

    const float* fsrc = (dir == 0) ? f0cl : f1cl;
    if (tid < 128) fvec[tid] = fsrc[(size_t)bn * CC + tid];

    float e  = embt[b];
    float sc = (dir == 0) ? (1.0f / e) : (1.0f / (1.0f - e));
    const float* fl = (dir == 0) ? flow1 : flow0;
    float fx = fl[((size_t)(b * 2 + 0) * HH + y) * WW + x];
    float fy = fl[((size_t)(b * 2 + 1) * HH + y) * WW + x];
    float inv = 1.0f / (float)(1 << lvl);
    float cx = ((float)x + fx * sc) * inv;
    float cy = ((float)y + fy * sc) * inv;
    float fx0 = floorf(cx), fy0 = floorf(cy);
    float wx = cx - fx0, wy = cy - fy0;
    int ix0 = (int)fx0, iy0 = (int)fy0;

    const float* map;
    if (dir == 0) map = (lvl == 0) ? f1cl : (lvl == 1) ? f1p1 : (lvl == 2) ? f1p2 : f1p3;
    else          map = (lvl == 0) ? f0cl : (lvl == 1) ? f0p1 : (lvl == 2) ? f0p2 : f0p3;
    int Hl = (lvl == 0) ? 60 : (lvl == 1) ? 30 : (lvl == 2) ? 15 : 7;
    int Wl = (lvl == 0) ? 108 : (lvl == 1) ? 54 : (lvl == 2) ? 27 : 13;

    int g   = lane >> 3;   // column-within-pass (window col)
    int sub = lane & 7;    // 16B chunk within column

    __syncthreads();

    const float4* fv4 = (const float4*)fvec;
    #pragma unroll
    for (int p = 0; p < 8; p++) {
        int c  = p * 8 + g;          // window index: row p, col g
        int xi = ix0 - 3 + g;
        int yi = iy0 - 3 + p;
        float part = 0.0f;
        if ((unsigned)xi < (unsigned)Wl && (unsigned)yi < (unsigned)Hl) {
            const float4* cp = (const float4*)(map + (((size_t)b * Hl + yi) * Wl + xi) * CC);
            #pragma unroll
            for (int it = 0; it < 4; it++) {
                float4 a = cp[it * 8 + sub];
                float4 f = fv4[it * 8 + sub];
                part += a.x * f.x + a.y * f.y + a.z * f.z + a.w * f.w;
            }
        }
        part += __shfl_xor(part, 1);
        part += __shfl_xor(part, 2);
        part += __shfl_xor(part, 4);
        if (sub == 0) dsh[lvl][c] = part * 0.08838834764831845f;  // 1/sqrt(128)
    }
    __syncthreads();

    if (lane < 49) {
        int r0 = lane / 7, c0 = lane % 7;
        float d00 = dsh[lvl][r0 * 8 + c0],       d01 = dsh[lvl][r0 * 8 + c0 + 1];
        float d10 = dsh[lvl][(r0 + 1) * 8 + c0], d11 = dsh[lvl][(r0 + 1) * 8 + c0 + 1];
        float val = d00 * (1.0f - wx) * (1.0f - wy) + d01 * wx * (1.0f - wy)
                  + d10 * (1.0f - wx) * wy          + d11 * wx * wy;
        int ch = dir * 196 + lvl * 49 + lane;
        corr_cl[(size_t)bn * 416 + ch] = f2b(val);
    }
}

// ---------------------------------------------------------------------------
// Pack conv weights (f32 OIHW, optional concat w1|w2 along O, zero-pad O and I)
// into MFMA B-fragment layout: chunk idx = ((tap*KSTEPS+ks)*TOTOCT+oct)*64+lane,
// 8 bf16 per chunk: oc = oct*16+(lane&15), k = ks*32+(lane>>4)*8+j, ic = k.
// ---------------------------------------------------------------------------
__global__ void packw_k(const float* __restrict__ w1, const float* __restrict__ w2,
                        int OC1, int OCreal, int Cin, int TAPS, int KSTEPS, int TOTOCT,
                        unsigned short* __restrict__ out) {
    int idx = blockIdx.x * 256 + threadIdx.x;
    int total = TAPS * KSTEPS * TOTOCT * 64;
    if (idx >= total) return;
    int lane = idx & 63;
    int rest = idx >> 6;
    int oct  = rest % TOTOCT;
    int rk   = rest / TOTOCT;
    int ks   = rk % KSTEPS;
    int tap  = rk / KSTEPS;
    int oc = oct * 16 + (lane & 15);
    int kb = ks * 32 + (lane >> 4) * 8;
    s16x8 o;
    #pragma unroll
    for (int j = 0; j < 8; j++) {
        int ic = kb + j;
        float val = 0.0f;
        if (oc < OCreal && ic < Cin) {
            val = (oc < OC1) ? w1[((size_t)oc * Cin + ic) * TAPS + tap]
                             : w2[((size_t)(oc - OC1) * Cin + ic) * TAPS + tap];
        }
        o[j] = (short)f2b(val);
    }
    *(s16x8*)(out + (size_t)idx * 8) = o;
}

// ---------------------------------------------------------------------------
// MFMA implicit-GEMM conv. M=pixels, N=oc.  A[i][k]: i=lane&15 (pixel),
// k=8*(lane>>4)+j. B from packed weights. D: col(oc)=lane&15, row(pixel)=
// 4*(lane>>4)+reg. Block 256 (4 waves, each 16 pixels). grid (102, OCG, B).
// ACT: 0 none 1 relu 2 sigmoid 3 tanh. EPI: 0 bf16 CL, 1 bf16 CL x2, 2 f32 CF.
// ---------------------------------------------------------------------------
template<int NOCT, int TAPS, int ACT, int EPI>
__launch_bounds__(256)
__global__ void convmf_k(const unsigned short* __restrict__ gin, int CS, int KSTEPS,
                         const unsigned short* __restrict__ wp,
                         const float* __restrict__ bias1, const float* __restrict__ bias2,
                         int OC1, int OCreal,
                         unsigned short* __restrict__ gout, int OCS, int ocoff,
                         unsigned short* __restrict__ gout2, int OCS2,
                         float* __restrict__ fout) {
    int lane = threadIdx.x & 63;
    int wv   = threadIdx.x >> 6;
    int pt   = blockIdx.x;
    int ocg  = blockIdx.y;
    int b    = blockIdx.z;
    int TOTOCT = gridDim.y * NOCT;
    int p0 = pt * 64 + wv * 16;
    int pa = p0 + (lane & 15);
    bool pv = pa < HWN;
    int py = pa / WW, px = pa - py * WW;
    const unsigned short* abase = gin + ((size_t)b * HWN + pa) * CS + (lane >> 4) * 8;
    int oct0 = ocg * NOCT;

    f32x4 acc[NOCT];
    #pragma unroll
    for (int t = 0; t < NOCT; t++) acc[t] = f32x4{0.f, 0.f, 0.f, 0.f};

    for (int tap = 0; tap < TAPS; tap++) {
        int dy = (TAPS == 1) ? 0 : (tap / 3 - 1);
        int dx = (TAPS == 1) ? 0 : (tap % 3 - 1);
        bool v = pv && ((unsigned)(py + dy) < (unsigned)HH) && ((unsigned)(px + dx) < (unsigned)WW);
        const unsigned short* ap = abase + (dy * WW + dx) * CS;
        const unsigned short* bp = wp + ((size_t)(tap * KSTEPS) * TOTOCT + oct0) * 512 + (size_t)lane * 8;
        for (int ks = 0; ks < KSTEPS; ks++) {
            s16x8 a = {};
            if (v) a = *(const s16x8*)(ap + ks * 32);
            const unsigned short* bpp = bp + (size_t)ks * TOTOCT * 512;
            #pragma unroll
            for (int t = 0; t < NOCT; t++) {
                s16x8 bf = *(const s16x8*)(bpp + (size_t)t * 512);
                acc[t] = __builtin_amdgcn_mfma_f32_16x16x32_bf16(a, bf, acc[t], 0, 0, 0);
            }
        }
    }

    int oc_l = lane & 15;
    int prow = p0 + (lane >> 4) * 4;
    #pragma unroll
    for (int t = 0; t < NOCT; t++) {
        int oc = (oct0 + t) * 16 + oc_l;
        float bs = 0.0f;
        if (oc < OCreal) bs = (oc < OC1) ? bias1[oc] : bias2[oc - OC1];
        #pragma unroll
        for (int r = 0; r < 4; r++) {
            int p = prow + r;
            if (p >= HWN) continue;
            float vv = acc[t][r] + bs;
            if (ACT == 1) vv = fmaxf(vv, 0.0f);
            else if (ACT == 2) vv = 1.0f / (1.0f + __expf(-vv));
            else if (ACT == 3) vv = tanhf(vv);
            if (EPI == 2) {
                if (oc < OCreal) fout[((size_t)b * OCreal + oc) * HWN + p] = vv;
            } else {
                unsigned short bvv = f2b(vv);
                gout[((size_t)b * HWN + p) * OCS + ocoff + oc] = bvv;
                if (EPI == 1) gout2[((size_t)b * HWN + p) * OCS2 + oc] = bvv;
            }
        }
    }
}

// ---------------------------------------------------------------------------
// flow conv (4->64, 3x3, relu), direct f32, writes gi ch 448..511 bf16
// ---------------------------------------------------------------------------
__global__ void flowconv_k(const float* __restrict__ flow0, const float* __restrict__ flow1,
                           const float* __restrict__ w, const float* __restrict__ bias,
                           unsigned short* __restrict__ gi) {
    int n = blockIdx.x * 64 + threadIdx.x;
    int b = blockIdx.y;
    if (n >= HWN) return;
    int y = n / WW, x = n - y * WW;
    float v[36];
    for (int c = 0; c < 4; c++) {
        const float* pl = (c < 2) ? flow0 + ((size_t)b * 2 + c) * HWN
                                  : flow1 + ((size_t)b * 2 + (c - 2)) * HWN;
        #pragma unroll
        for (int dy = -1; dy <= 1; dy++)
            #pragma unroll
            for (int dx = -1; dx <= 1; dx++) {
                int yy = y + dy, xx = x + dx;
                v[c * 9 + (dy + 1) * 3 + (dx + 1)] =
                    (((unsigned)yy < (unsigned)HH) && ((unsigned)xx < (unsigned)WW))
                        ? pl[(size_t)yy * WW + xx] : 0.0f;
            }
    }
    unsigned short* op = gi + ((size_t)b * HWN + n) * 512 + 448;
    for (int oc0 = 0; oc0 < 64; oc0 += 8) {
        s16x8 o;
        #pragma unroll
        for (int j = 0; j < 8; j++) {
            int oc = oc0 + j;
            const float* wpp = w + (size_t)oc * 36;
            float a = bias[oc];
            #pragma unroll
            for (int k = 0; k < 36; k++) a += wpp[k] * v[k];
            o[j] = (short)f2b(fmaxf(a, 0.0f));
        }
        *(s16x8*)(op + oc0) = o;
    }
}

// ---------------------------------------------------------------------------
// rh: gi[ch 0..191] = r * h     (r = sigmoid'd, zr ch192..383; h from hsep)
// ---------------------------------------------------------------------------
__global__ void rh_k(const unsigned short* __restrict__ zr, const unsigned short* __restrict__ hs,
                     unsigned short* __restrict__ gi) {
    int idx = blockIdx.x * 256 + threadIdx.x;
    if (idx >= BB * HWN * 24) return;
    int n = idx / 24, c8 = (idx % 24) * 8;
    s16x8 r = *(const s16x8*)(zr + (size_t)n * 384 + 192 + c8);
    s16x8 h = *(const s16x8*)(hs + (size_t)n * 192 + c8);
    s16x8 o;
    #pragma unroll
    for (int j = 0; j < 8; j++)
        o[j] = (short)f2b(b2f((unsigned short)r[j]) * b2f((unsigned short)h[j]));
    *(s16x8*)(gi + (size_t)n * 512 + c8) = o;
}

// ---------------------------------------------------------------------------
// hnew: gi[ch 0..191] = (1-z)*h + z*q
// ---------------------------------------------------------------------------
__global__ void hnew_k(const unsigned short* __restrict__ zr, const unsigned short* __restrict__ hs,
                       const unsigned short* __restrict__ q, unsigned short* __restrict__ gi) {
    int idx = blockIdx.x * 256 + threadIdx.x;
    if (idx >= BB * HWN * 24) return;
    int n = idx / 24, c8 = (idx % 24) * 8;
    s16x8 z = *(const s16x8*)(zr + (size_t)n * 384 + c8);
    s16x8 h = *(const s16x8*)(hs + (size_t)n * 192 + c8);
    s16x8 qq = *(const s16x8*)(q + (size_t)n * 192 + c8);
    s16x8 o;
    #pragma unroll
    for (int j = 0; j < 8; j++) {
        float zf = b2f((unsigned short)z[j]);
        o[j] = (short)f2b((1.0f - zf) * b2f((unsigned short)h[j]) + zf * b2f((unsigned short)qq[j]));
    }
    *(s16x8*)(gi + (size_t)n * 512 + c8) = o;
}

// ---------------------------------------------------------------------------
extern "C" void kernel_launch(void* const* d_in, const int* in_sizes, int n_in,
                              void* d_out, int out_size, void* d_ws, size_t ws_size,
                              hipStream_t stream) {
    const float* fmap0 = (const float*)d_in[0];
    const float* fmap1 = (const float*)d_in[1];
    const float* ft    = (const float*)d_in[2];
    const float* flow0 = (const float*)d_in[3];
    const float* flow1 = (const float*)d_in[4];
    const float* embt  = (const float*)d_in[5];
    const float* w_corr = (const float*)d_in[6];
    const float* b_corr = (const float*)d_in[7];
    const float* w_flow = (const float*)d_in[8];
    const float* b_flow = (const float*)d_in[9];
    const float* w_ctx  = (const float*)d_in[10];
    const float* b_ctx  = (const float*)d_in[11];
    const float* w_z    = (const float*)d_in[12];
    const float* b_z    = (const float*)d_in[13];
    const float* w_r    = (const float*)d_in[14];
    const float* b_r    = (const float*)d_in[15];
    const float* w_q    = (const float*)d_in[16];
    const float* b_q    = (const float*)d_in[17];
    const float* w_fh   = (const float*)d_in[18];
    const float* b_fh   = (const float*)d_in[19];
    const float* w_dh   = (const float*)d_in[20];
    const float* b_dh   = (const float*)d_in[21];
    float* out = (float*)d_out;

    char* ws = (char*)d_ws;
    size_t off = 0;
    auto alloc = [&](size_t bytes) { size_t o = off; off += (bytes + 255) & ~(size_t)255; return o; };

    float* f0cl = (float*)(ws + alloc((size_t)BB * HWN * CC * 4));
    float* f1cl = (float*)(ws + alloc((size_t)BB * HWN * CC * 4));
    float* f0p1 = (float*)(ws + alloc((size_t)BB * 30 * 54 * CC * 4));
    float* f0p2 = (float*)(ws + alloc((size_t)BB * 15 * 27 * CC * 4));
    float* f0p3 = (float*)(ws + alloc((size_t)BB * 7 * 13 * CC * 4));
    float* f1p1 = (float*)(ws + alloc((size_t)BB * 30 * 54 * CC * 4));
    float* f1p2 = (float*)(ws + alloc((size_t)BB * 15 * 27 * CC * 4));
    float* f1p3 = (float*)(ws + alloc((size_t)BB * 7 * 13 * CC * 4));
    unsigned short* ftcl   = (unsigned short*)(ws + alloc((size_t)BB * HWN * 128 * 2));
    unsigned short* corrcl = (unsigned short*)(ws + alloc((size_t)BB * HWN * 416 * 2));
    unsigned short* gi     = (unsigned short*)(ws + alloc((size_t)BB * HWN * 512 * 2));
    unsigned short* hsep   = (unsigned short*)(ws + alloc((size_t)BB * HWN * 192 * 2));
    unsigned short* zrbuf  = (unsigned short*)(ws + alloc((size_t)BB * HWN * 384 * 2));
    unsigned short* qbuf   = (unsigned short*)(ws + alloc((size_t)BB * HWN * 192 * 2));
    unsigned short* wpzr   = (unsigned short*)(ws + alloc((size_t)9 * 16 * 24 * 64 * 8 * 2));
    unsigned short* wpq    = (unsigned short*)(ws + alloc((size_t)9 * 16 * 12 * 64 * 8 * 2));
    unsigned short* wpctx  = (unsigned short*)(ws + alloc((size_t)9 * 4 * 12 * 64 * 8 * 2));
    unsigned short* wpdh   = (unsigned short*)(ws + alloc((size_t)9 * 6 * 8 * 64 * 8 * 2));
    unsigned short* wpcorr = (unsigned short*)(ws + alloc((size_t)1 * 13 * 16 * 64 * 8 * 2));

    // weight packing
    packw_k<<<dim3((9 * 16 * 24 * 64 + 255) / 256), dim3(256), 0, stream>>>(
        w_z, w_r, 192, 384, 512, 9, 16, 24, wpzr);
    packw_k<<<dim3((9 * 16 * 12 * 64 + 255) / 256), dim3(256), 0, stream>>>(
        w_q, w_q, 192, 192, 512, 9, 16, 12, wpq);
    packw_k<<<dim3((9 * 4 * 12 * 64 + 255) / 256), dim3(256), 0, stream>>>(
        w_ctx, w_ctx, 192, 192, 112, 9, 4, 12, wpctx);
    packw_k<<<dim3((9 * 6 * 8 * 64 + 255) / 256), dim3(256), 0, stream>>>(
        w_dh, w_fh, 112, 116, 192, 9, 6, 8, wpdh);
    packw_k<<<dim3((1 * 13 * 16 * 64 + 255) / 256), dim3(256), 0, stream>>>(
        w_corr, w_corr, 256, 256, 392, 1, 13, 16, wpcorr);

    // channel-last transposes + pyramids
    f2cl_k<<<dim3((HWN + 63) / 64, BB), dim3(64), 0, stream>>>(fmap0, f0cl);
    f2cl_k<<<dim3((HWN + 63) / 64, BB), dim3(64), 0, stream>>>(fmap1, f1cl);
    ft2cl_k<<<dim3((HWN + 63) / 64, BB), dim3(64), 0, stream>>>(ft, ftcl);
    pool_k<<<dim3(BB * 30 * 54), dim3(128), 0, stream>>>(f0cl, f0p1, 60, 108, 30, 54);
    pool_k<<<dim3(BB * 15 * 27), dim3(128), 0, stream>>>(f0p1, f0p2, 30, 54, 15, 27);
    pool_k<<<dim3(BB * 7 * 13),  dim3(128), 0, stream>>>(f0p2, f0p3, 15, 27, 7, 13);
    pool_k<<<dim3(BB * 30 * 54), dim3(128), 0, stream>>>(f1cl, f1p1, 60, 108, 30, 54);
    pool_k<<<dim3(BB * 15 * 27), dim3(128), 0, stream>>>(f1p1, f1p2, 30, 54, 15, 27);
    pool_k<<<dim3(BB * 7 * 13),  dim3(128), 0, stream>>>(f1p2, f1p3, 15, 27, 7, 13);

    // lookup -> corr_cl bf16 [B][HW][416]   (4 levels per block, coop columns)
    lookup_k<<<dim3(BB * HWN, 2), dim3(256), 0, stream>>>(
        f0cl, f1cl, f0p1, f0p2, f0p3, f1p1, f1p2, f1p3,
        flow0, flow1, embt, corrcl);

    // ffeat -> gi ch 448..511
    flowconv_k<<<dim3((HWN + 63) / 64, BB), dim3(64), 0, stream>>>(flow0, flow1, w_flow, b_flow, gi);

    // cfeat = relu(1x1) -> gi ch 192..447
    convmf_k<4, 1, 1, 0><<<dim3(102, 4, BB), dim3(256), 0, stream>>>(
        corrcl, 416, 13, wpcorr, b_corr, b_corr, 256, 256, gi, 512, 192, nullptr, 0, nullptr);

    // h = tanh(ctx conv) -> gi ch 0..191 AND hsep
    convmf_k<3, 9, 3, 1><<<dim3(102, 4, BB), dim3(256), 0, stream>>>(
        ftcl, 128, 4, wpctx, b_ctx, b_ctx, 192, 192, gi, 512, 0, hsep, 192, nullptr);

    // z|r = sigmoid(conv(gi)) -> zrbuf [B][HW][384]
    convmf_k<6, 9, 2, 0><<<dim3(102, 4, BB), dim3(256), 0, stream>>>(
        gi, 512, 16, wpzr, b_z, b_r, 192, 384, zrbuf, 384, 0, nullptr, 0, nullptr);

    // gi ch0..191 = r*h
    rh_k<<<dim3((BB * HWN * 24 + 255) / 256), dim3(256), 0, stream>>>(zrbuf, hsep, gi);

    // q = tanh(conv(gi)) -> qbuf
    convmf_k<3, 9, 3, 0><<<dim3(102, 4, BB), dim3(256), 0, stream>>>(
        gi, 512, 16, wpq, b_q, b_q, 192, 192, qbuf, 192, 0, nullptr, 0, nullptr);

    // gi ch0..191 = (1-z)h + z q
    hnew_k<<<dim3((BB * HWN * 24 + 255) / 256), dim3(256), 0, stream>>>(zrbuf, hsep, qbuf, gi);

    // out = [dh(112); fh(4)] conv of h' (gi ch0..191, stride 512) -> f32 CF
    convmf_k<2, 9, 0, 2><<<dim3(102, 4, BB), dim3(256), 0, stream>>>(
        gi, 512, 6, wpdh, b_dh, b_fh, 112, 116, nullptr, 0, 0, nullptr, 0, out);
}

// Round 7
// 530.569 us; speedup vs baseline: 7.4278x; 1.1085x over previous
//
#include <hip/hip_runtime.h>
#include <hip/hip_bf16.h>
#include <math.h>

#define BB 2
#define CC 128
#define HH 60
#define WW 108
#define HWN (HH*WW)

typedef __attribute__((ext_vector_type(8))) short s16x8;
typedef __attribute__((ext_vector_type(4))) float f32x4;

__device__ __forceinline__ unsigned short f2b(float f) {
    union { float f; unsigned int u; } v; v.f = f;
    unsigned int r = (v.u + 0x7FFFu + ((v.u >> 16) & 1u)) >> 16;
    return (unsigned short)r;
}
__device__ __forceinline__ float b2f(unsigned short b) {
    union { unsigned int u; float f; } v; v.u = ((unsigned int)b) << 16;
    return v.f;
}

// ---------------------------------------------------------------------------
// fmap [B][128][HW] f32 -> [B][HW][128] f32 (channel-last, for lookup)
// ---------------------------------------------------------------------------
__global__ void f2cl_k(const float* __restrict__ in, float* __restrict__ out) {
    int n = blockIdx.x * 64 + threadIdx.x;
    int b = blockIdx.y;
    if (n >= HWN) return;
    const float* ip = in + (size_t)b * CC * HWN + n;
    float* op = out + ((size_t)b * HWN + n) * CC;
    for (int c0 = 0; c0 < CC; c0 += 4) {
        float4 o;
        o.x = ip[(size_t)(c0 + 0) * HWN];
        o.y = ip[(size_t)(c0 + 1) * HWN];
        o.z = ip[(size_t)(c0 + 2) * HWN];
        o.w = ip[(size_t)(c0 + 3) * HWN];
        *(float4*)(op + c0) = o;
    }
}

// ---------------------------------------------------------------------------
// ft [B][112][HW] f32 -> [B][HW][128] bf16 (pad 112..127 zero)
// ---------------------------------------------------------------------------
__global__ void ft2cl_k(const float* __restrict__ ft, unsigned short* __restrict__ out) {
    int n = blockIdx.x * 64 + threadIdx.x;
    int b = blockIdx.y;
    if (n >= HWN) return;
    const float* ip = ft + (size_t)b * 112 * HWN + n;
    unsigned short* op = out + ((size_t)b * HWN + n) * 128;
    for (int c0 = 0; c0 < 112; c0 += 8) {
        s16x8 o;
        #pragma unroll
        for (int j = 0; j < 8; j++) o[j] = (short)f2b(ip[(size_t)(c0 + j) * HWN]);
        *(s16x8*)(op + c0) = o;
    }
    s16x8 z = {};
    *(s16x8*)(op + 112) = z;
    *(s16x8*)(op + 120) = z;
}

// ---------------------------------------------------------------------------
// 2x2 avg pool on channel-last f32 maps
// ---------------------------------------------------------------------------
__global__ void pool_k(const float* __restrict__ in, float* __restrict__ out,
                       int Hi, int Wi, int Ho, int Wo) {
    int bp = blockIdx.x;
    int b  = bp / (Ho * Wo);
    int p  = bp % (Ho * Wo);
    int yo = p / Wo, xo = p % Wo;
    int c  = threadIdx.x;
    const float* i0 = in + (((size_t)b * Hi + 2 * yo) * Wi + 2 * xo) * CC;
    float v = i0[c] + i0[CC + c] + i0[(size_t)Wi * CC + c] + i0[(size_t)Wi * CC + CC + c];
    out[(((size_t)b * Ho + yo) * Wo + xo) * CC + c] = 0.25f * v;
}

// ---------------------------------------------------------------------------
// Correlation pyramid lookup -> corr_cl [B][HW][416] bf16 (ch 392..415 unused)
// grid: (B*HW, 2) block 256. blockIdx.y = dir; wave (tid>>6) = level.
// ---------------------------------------------------------------------------
__global__ void lookup_k(const float* __restrict__ f0cl, const float* __restrict__ f1cl,
                         const float* __restrict__ f0p1, const float* __restrict__ f0p2,
                         const float* __restrict__ f0p3,
                         const float* __restrict__ f1p1, const float* __restrict__ f1p2,
                         const float* __restrict__ f1p3,
                         const float* __restrict__ flow0, const float* __restrict__ flow1,
                         const float* __restrict__ embt, unsigned short* __restrict__ corr_cl) {
    int bn = blockIdx.x;
    int b  = bn / HWN;
    int n  = bn % HWN;
    int y  = n / WW, x = n % WW;
    int dir = blockIdx.y;
    int tid = threadIdx.x;
    int lane = tid & 63;
    int lvl  = tid >> 6;

    __shared__ __align__(16) float fvec[CC];
    __shared__ float dsh[4][64];

    const float* fsrc = (dir == 0) ? f0cl : f1cl;
    if (tid < 128) fvec[tid] = fsrc[(size_t)bn * CC + tid];

    float e  = embt[b];
    float sc = (dir == 0) ? (1.0f / e) : (1.0f / (1.0f - e));
    const float* fl = (dir == 0) ? flow1 : flow0;
    float fx = fl[((size_t)(b * 2 + 0) * HH + y) * WW + x];
    float fy = fl[((size_t)(b * 2 + 1) * HH + y) * WW + x];
    float inv = 1.0f / (float)(1 << lvl);
    float cx = ((float)x + fx * sc) * inv;
    float cy = ((float)y + fy * sc) * inv;
    float fx0 = floorf(cx), fy0 = floorf(cy);
    float wx = cx - fx0, wy = cy - fy0;
    int ix0 = (int)fx0, iy0 = (int)fy0;

    const float* map;
    if (dir == 0) map = (lvl == 0) ? f1cl : (lvl == 1) ? f1p1 : (lvl == 2) ? f1p2 : f1p3;
    else          map = (lvl == 0) ? f0cl : (lvl == 1) ? f0p1 : (lvl == 2) ? f0p2 : f0p3;
    int Hl = (lvl == 0) ? 60 : (lvl == 1) ? 30 : (lvl == 2) ? 15 : 7;
    int Wl = (lvl == 0) ? 108 : (lvl == 1) ? 54 : (lvl == 2) ? 27 : 13;

    int g   = lane >> 3;   // window col
    int sub = lane & 7;    // 16B chunk within column

    __syncthreads();

    const float4* fv4 = (const float4*)fvec;
    #pragma unroll
    for (int p = 0; p < 8; p++) {
        int c  = p * 8 + g;
        int xi = ix0 - 3 + g;
        int yi = iy0 - 3 + p;
        float part = 0.0f;
        if ((unsigned)xi < (unsigned)Wl && (unsigned)yi < (unsigned)Hl) {
            const float4* cp = (const float4*)(map + (((size_t)b * Hl + yi) * Wl + xi) * CC);
            #pragma unroll
            for (int it = 0; it < 4; it++) {
                float4 a = cp[it * 8 + sub];
                float4 f = fv4[it * 8 + sub];
                part += a.x * f.x + a.y * f.y + a.z * f.z + a.w * f.w;
            }
        }
        part += __shfl_xor(part, 1);
        part += __shfl_xor(part, 2);
        part += __shfl_xor(part, 4);
        if (sub == 0) dsh[lvl][c] = part * 0.08838834764831845f;  // 1/sqrt(128)
    }
    __syncthreads();

    if (lane < 49) {
        int r0 = lane / 7, c0 = lane % 7;
        float d00 = dsh[lvl][r0 * 8 + c0],       d01 = dsh[lvl][r0 * 8 + c0 + 1];
        float d10 = dsh[lvl][(r0 + 1) * 8 + c0], d11 = dsh[lvl][(r0 + 1) * 8 + c0 + 1];
        float val = d00 * (1.0f - wx) * (1.0f - wy) + d01 * wx * (1.0f - wy)
                  + d10 * (1.0f - wx) * wy          + d11 * wx * wy;
        int ch = dir * 196 + lvl * 49 + lane;
        corr_cl[(size_t)bn * 416 + ch] = f2b(val);
    }
}

// ---------------------------------------------------------------------------
// Pack conv weights into MFMA B-fragment layout (unchanged layout):
// chunk idx = ((tap*KSTEPS+ks)*TOTOCT+oct)*64+lane; 8 bf16/chunk:
// oc = oct*16+(lane&15), ic = ks*32+(lane>>4)*8+j.
// ---------------------------------------------------------------------------
__global__ void packw_k(const float* __restrict__ w1, const float* __restrict__ w2,
                        int OC1, int OCreal, int Cin, int TAPS, int KSTEPS, int TOTOCT,
                        unsigned short* __restrict__ out) {
    int idx = blockIdx.x * 256 + threadIdx.x;
    int total = TAPS * KSTEPS * TOTOCT * 64;
    if (idx >= total) return;
    int lane = idx & 63;
    int rest = idx >> 6;
    int oct  = rest % TOTOCT;
    int rk   = rest / TOTOCT;
    int ks   = rk % KSTEPS;
    int tap  = rk / KSTEPS;
    int oc = oct * 16 + (lane & 15);
    int kb = ks * 32 + (lane >> 4) * 8;
    s16x8 o;
    #pragma unroll
    for (int j = 0; j < 8; j++) {
        int ic = kb + j;
        float val = 0.0f;
        if (oc < OCreal && ic < Cin) {
            val = (oc < OC1) ? w1[((size_t)oc * Cin + ic) * TAPS + tap]
                             : w2[((size_t)(oc - OC1) * Cin + ic) * TAPS + tap];
        }
        o[j] = (short)f2b(val);
    }
    *(s16x8*)(out + (size_t)idx * 8) = o;
}

// ---------------------------------------------------------------------------
// MFMA implicit-GEMM conv, multi-M-fragment version.
// Wave handles MF x 16 pixels x NOCT x 16 oc. Block = 4 waves stacked on M.
// Template KSTEPS/TAPS/NCS -> fully unrolled, pipelinable inner loops.
// ACT: 0 none 1 relu 2 sigmoid 3 tanh. EPI: 0 bf16 CL, 1 bf16 CL x2, 2 f32 CF.
// ---------------------------------------------------------------------------
template<int NOCT, int MF, int TAPS, int KSTEPS, int NCS, int ACT, int EPI>
__launch_bounds__(256)
__global__ void convmf_k(const unsigned short* __restrict__ gin,
                         const unsigned short* __restrict__ wp,
                         const float* __restrict__ bias1, const float* __restrict__ bias2,
                         int OC1, int OCreal, int TOTOCT,
                         unsigned short* __restrict__ gout, int OCS, int ocoff,
                         unsigned short* __restrict__ gout2, int OCS2,
                         float* __restrict__ fout) {
    int lane = threadIdx.x & 63;
    int wv   = threadIdx.x >> 6;
    int ocg  = blockIdx.y;
    int b    = blockIdx.z;
    int p0   = (blockIdx.x * 4 + wv) * (MF * 16);
    int oct0 = ocg * NOCT;
    int arow = lane & 15;
    int koff = (lane >> 4) * 8;

    // per-M-frag pixel info
    int pa[MF]; int py[MF]; int px[MF]; bool pv[MF];
    #pragma unroll
    for (int m = 0; m < MF; m++) {
        pa[m] = p0 + m * 16 + arow;
        pv[m] = pa[m] < HWN;
        py[m] = pa[m] / WW; px[m] = pa[m] - py[m] * WW;
    }

    f32x4 acc[MF][NOCT];
    #pragma unroll
    for (int m = 0; m < MF; m++)
        #pragma unroll
        for (int t = 0; t < NOCT; t++) acc[m][t] = f32x4{0.f, 0.f, 0.f, 0.f};

    #pragma unroll
    for (int tap = 0; tap < TAPS; tap++) {
        const int dy = (TAPS == 1) ? 0 : (tap / 3 - 1);
        const int dx = (TAPS == 1) ? 0 : (tap % 3 - 1);
        const unsigned short* ap[MF]; bool v[MF];
        #pragma unroll
        for (int m = 0; m < MF; m++) {
            v[m] = pv[m] && ((unsigned)(py[m] + dy) < (unsigned)HH)
                         && ((unsigned)(px[m] + dx) < (unsigned)WW);
            ap[m] = gin + ((size_t)b * HWN + pa[m] + dy * WW + dx) * NCS + koff;
        }
        const unsigned short* bp = wp
            + ((size_t)(tap * KSTEPS) * TOTOCT + oct0) * 512 + (size_t)lane * 8;
        #pragma unroll
        for (int ks = 0; ks < KSTEPS; ks++) {
            s16x8 a[MF];
            #pragma unroll
            for (int m = 0; m < MF; m++) {
                a[m] = s16x8{};
                if (v[m]) a[m] = *(const s16x8*)(ap[m] + ks * 32);
            }
            s16x8 bf[NOCT];
            const unsigned short* bpp = bp + (size_t)ks * TOTOCT * 512;
            #pragma unroll
            for (int t = 0; t < NOCT; t++) bf[t] = *(const s16x8*)(bpp + (size_t)t * 512);
            #pragma unroll
            for (int m = 0; m < MF; m++)
                #pragma unroll
                for (int t = 0; t < NOCT; t++)
                    acc[m][t] = __builtin_amdgcn_mfma_f32_16x16x32_bf16(a[m], bf[t], acc[m][t], 0, 0, 0);
        }
    }

    int oc_l = lane & 15;
    #pragma unroll
    for (int t = 0; t < NOCT; t++) {
        int oc = (oct0 + t) * 16 + oc_l;
        float bs = 0.0f;
        if (oc < OCreal) bs = (oc < OC1) ? bias1[oc] : bias2[oc - OC1];
        #pragma unroll
        for (int m = 0; m < MF; m++) {
            int prow = p0 + m * 16 + (lane >> 4) * 4;
            #pragma unroll
            for (int r = 0; r < 4; r++) {
                int p = prow + r;
                if (p >= HWN) continue;
                float vv = acc[m][t][r] + bs;
                if (ACT == 1) vv = fmaxf(vv, 0.0f);
                else if (ACT == 2) vv = 1.0f / (1.0f + __expf(-vv));
                else if (ACT == 3) vv = tanhf(vv);
                if (EPI == 2) {
                    if (oc < OCreal) fout[((size_t)b * OCreal + oc) * HWN + p] = vv;
                } else {
                    unsigned short bvv = f2b(vv);
                    gout[((size_t)b * HWN + p) * OCS + ocoff + oc] = bvv;
                    if (EPI == 1) gout2[((size_t)b * HWN + p) * OCS2 + oc] = bvv;
                }
            }
        }
    }
}

// ---------------------------------------------------------------------------
// flow conv (4->64, 3x3, relu), direct f32, writes gi ch 448..511 bf16
// ---------------------------------------------------------------------------
__global__ void flowconv_k(const float* __restrict__ flow0, const float* __restrict__ flow1,
                           const float* __restrict__ w, const float* __restrict__ bias,
                           unsigned short* __restrict__ gi) {
    int n = blockIdx.x * 64 + threadIdx.x;
    int b = blockIdx.y;
    if (n >= HWN) return;
    int y = n / WW, x = n - y * WW;
    float v[36];
    for (int c = 0; c < 4; c++) {
        const float* pl = (c < 2) ? flow0 + ((size_t)b * 2 + c) * HWN
                                  : flow1 + ((size_t)b * 2 + (c - 2)) * HWN;
        #pragma unroll
        for (int dy = -1; dy <= 1; dy++)
            #pragma unroll
            for (int dx = -1; dx <= 1; dx++) {
                int yy = y + dy, xx = x + dx;
                v[c * 9 + (dy + 1) * 3 + (dx + 1)] =
                    (((unsigned)yy < (unsigned)HH) && ((unsigned)xx < (unsigned)WW))
                        ? pl[(size_t)yy * WW + xx] : 0.0f;
            }
    }
    unsigned short* op = gi + ((size_t)b * HWN + n) * 512 + 448;
    for (int oc0 = 0; oc0 < 64; oc0 += 8) {
        s16x8 o;
        #pragma unroll
        for (int j = 0; j < 8; j++) {
            int oc = oc0 + j;
            const float* wpp = w + (size_t)oc * 36;
            float a = bias[oc];
            #pragma unroll
            for (int k = 0; k < 36; k++) a += wpp[k] * v[k];
            o[j] = (short)f2b(fmaxf(a, 0.0f));
        }
        *(s16x8*)(op + oc0) = o;
    }
}

// ---------------------------------------------------------------------------
// rh: gi[ch 0..191] = r * h
// ---------------------------------------------------------------------------
__global__ void rh_k(const unsigned short* __restrict__ zr, const unsigned short* __restrict__ hs,
                     unsigned short* __restrict__ gi) {
    int idx = blockIdx.x * 256 + threadIdx.x;
    if (idx >= BB * HWN * 24) return;
    int n = idx / 24, c8 = (idx % 24) * 8;
    s16x8 r = *(const s16x8*)(zr + (size_t)n * 384 + 192 + c8);
    s16x8 h = *(const s16x8*)(hs + (size_t)n * 192 + c8);
    s16x8 o;
    #pragma unroll
    for (int j = 0; j < 8; j++)
        o[j] = (short)f2b(b2f((unsigned short)r[j]) * b2f((unsigned short)h[j]));
    *(s16x8*)(gi + (size_t)n * 512 + c8) = o;
}

// ---------------------------------------------------------------------------
// hnew: gi[ch 0..191] = (1-z)*h + z*q
// ---------------------------------------------------------------------------
__global__ void hnew_k(const unsigned short* __restrict__ zr, const unsigned short* __restrict__ hs,
                       const unsigned short* __restrict__ q, unsigned short* __restrict__ gi) {
    int idx = blockIdx.x * 256 + threadIdx.x;
    if (idx >= BB * HWN * 24) return;
    int n = idx / 24, c8 = (idx % 24) * 8;
    s16x8 z = *(const s16x8*)(zr + (size_t)n * 384 + c8);
    s16x8 h = *(const s16x8*)(hs + (size_t)n * 192 + c8);
    s16x8 qq = *(const s16x8*)(q + (size_t)n * 192 + c8);
    s16x8 o;
    #pragma unroll
    for (int j = 0; j < 8; j++) {
        float zf = b2f((unsigned short)z[j]);
        o[j] = (short)f2b((1.0f - zf) * b2f((unsigned short)h[j]) + zf * b2f((unsigned short)qq[j]));
    }
    *(s16x8*)(gi + (size_t)n * 512 + c8) = o;
}

// ---------------------------------------------------------------------------
extern "C" void kernel_launch(void* const* d_in, const int* in_sizes, int n_in,
                              void* d_out, int out_size, void* d_ws, size_t ws_size,
                              hipStream_t stream) {
    const float* fmap0 = (const float*)d_in[0];
    const float* fmap1 = (const float*)d_in[1];
    const float* ft    = (const float*)d_in[2];
    const float* flow0 = (const float*)d_in[3];
    const float* flow1 = (const float*)d_in[4];
    const float* embt  = (const float*)d_in[5];
    const float* w_corr = (const float*)d_in[6];
    const float* b_corr = (const float*)d_in[7];
    const float* w_flow = (const float*)d_in[8];
    const float* b_flow = (const float*)d_in[9];
    const float* w_ctx  = (const float*)d_in[10];
    const float* b_ctx  = (const float*)d_in[11];
    const float* w_z    = (const float*)d_in[12];
    const float* b_z    = (const float*)d_in[13];
    const float* w_r    = (const float*)d_in[14];
    const float* b_r    = (const float*)d_in[15];
    const float* w_q    = (const float*)d_in[16];
    const float* b_q    = (const float*)d_in[17];
    const float* w_fh   = (const float*)d_in[18];
    const float* b_fh   = (const float*)d_in[19];
    const float* w_dh   = (const float*)d_in[20];
    const float* b_dh   = (const float*)d_in[21];
    float* out = (float*)d_out;

    char* ws = (char*)d_ws;
    size_t off = 0;
    auto alloc = [&](size_t bytes) { size_t o = off; off += (bytes + 255) & ~(size_t)255; return o; };

    float* f0cl = (float*)(ws + alloc((size_t)BB * HWN * CC * 4));
    float* f1cl = (float*)(ws + alloc((size_t)BB * HWN * CC * 4));
    float* f0p1 = (float*)(ws + alloc((size_t)BB * 30 * 54 * CC * 4));
    float* f0p2 = (float*)(ws + alloc((size_t)BB * 15 * 27 * CC * 4));
    float* f0p3 = (float*)(ws + alloc((size_t)BB * 7 * 13 * CC * 4));
    float* f1p1 = (float*)(ws + alloc((size_t)BB * 30 * 54 * CC * 4));
    float* f1p2 = (float*)(ws + alloc((size_t)BB * 15 * 27 * CC * 4));
    float* f1p3 = (float*)(ws + alloc((size_t)BB * 7 * 13 * CC * 4));
    unsigned short* ftcl   = (unsigned short*)(ws + alloc((size_t)BB * HWN * 128 * 2));
    unsigned short* corrcl = (unsigned short*)(ws + alloc((size_t)BB * HWN * 416 * 2));
    unsigned short* gi     = (unsigned short*)(ws + alloc((size_t)BB * HWN * 512 * 2));
    unsigned short* hsep   = (unsigned short*)(ws + alloc((size_t)BB * HWN * 192 * 2));
    unsigned short* zrbuf  = (unsigned short*)(ws + alloc((size_t)BB * HWN * 384 * 2));
    unsigned short* qbuf   = (unsigned short*)(ws + alloc((size_t)BB * HWN * 192 * 2));
    unsigned short* wpzr   = (unsigned short*)(ws + alloc((size_t)9 * 16 * 24 * 64 * 8 * 2));
    unsigned short* wpq    = (unsigned short*)(ws + alloc((size_t)9 * 16 * 12 * 64 * 8 * 2));
    unsigned short* wpctx  = (unsigned short*)(ws + alloc((size_t)9 * 4 * 12 * 64 * 8 * 2));
    unsigned short* wpdh   = (unsigned short*)(ws + alloc((size_t)9 * 6 * 8 * 64 * 8 * 2));
    unsigned short* wpcorr = (unsigned short*)(ws + alloc((size_t)1 * 13 * 16 * 64 * 8 * 2));

    // weight packing
    packw_k<<<dim3((9 * 16 * 24 * 64 + 255) / 256), dim3(256), 0, stream>>>(
        w_z, w_r, 192, 384, 512, 9, 16, 24, wpzr);
    packw_k<<<dim3((9 * 16 * 12 * 64 + 255) / 256), dim3(256), 0, stream>>>(
        w_q, w_q, 192, 192, 512, 9, 16, 12, wpq);
    packw_k<<<dim3((9 * 4 * 12 * 64 + 255) / 256), dim3(256), 0, stream>>>(
        w_ctx, w_ctx, 192, 192, 112, 9, 4, 12, wpctx);
    packw_k<<<dim3((9 * 6 * 8 * 64 + 255) / 256), dim3(256), 0, stream>>>(
        w_dh, w_fh, 112, 116, 192, 9, 6, 8, wpdh);
    packw_k<<<dim3((1 * 13 * 16 * 64 + 255) / 256), dim3(256), 0, stream>>>(
        w_corr, w_corr, 256, 256, 392, 1, 13, 16, wpcorr);

    // channel-last transposes + pyramids
    f2cl_k<<<dim3((HWN + 63) / 64, BB), dim3(64), 0, stream>>>(fmap0, f0cl);
    f2cl_k<<<dim3((HWN + 63) / 64, BB), dim3(64), 0, stream>>>(fmap1, f1cl);
    ft2cl_k<<<dim3((HWN + 63) / 64, BB), dim3(64), 0, stream>>>(ft, ftcl);
    pool_k<<<dim3(BB * 30 * 54), dim3(128), 0, stream>>>(f0cl, f0p1, 60, 108, 30, 54);
    pool_k<<<dim3(BB * 15 * 27), dim3(128), 0, stream>>>(f0p1, f0p2, 30, 54, 15, 27);
    pool_k<<<dim3(BB * 7 * 13),  dim3(128), 0, stream>>>(f0p2, f0p3, 15, 27, 7, 13);
    pool_k<<<dim3(BB * 30 * 54), dim3(128), 0, stream>>>(f1cl, f1p1, 60, 108, 30, 54);
    pool_k<<<dim3(BB * 15 * 27), dim3(128), 0, stream>>>(f1p1, f1p2, 30, 54, 15, 27);
    pool_k<<<dim3(BB * 7 * 13),  dim3(128), 0, stream>>>(f1p2, f1p3, 15, 27, 7, 13);

    // lookup -> corr_cl bf16 [B][HW][416]
    lookup_k<<<dim3(BB * HWN, 2), dim3(256), 0, stream>>>(
        f0cl, f1cl, f0p1, f0p2, f0p3, f1p1, f1p2, f1p3,
        flow0, flow1, embt, corrcl);

    // ffeat -> gi ch 448..511
    flowconv_k<<<dim3((HWN + 63) / 64, BB), dim3(64), 0, stream>>>(flow0, flow1, w_flow, b_flow, gi);

    // cfeat = relu(1x1 conv corrcl) -> gi ch 192..447  (N=256, TOTOCT=16, NOCT=4, MF=2)
    convmf_k<4, 2, 1, 13, 416, 1, 0><<<dim3(51, 4, BB), dim3(256), 0, stream>>>(
        corrcl, wpcorr, b_corr, b_corr, 256, 256, 16, gi, 512, 192, nullptr, 0, nullptr);

    // h = tanh(ctx conv ftcl) -> gi ch 0..191 AND hsep  (N=192, TOTOCT=12, NOCT=3, MF=2)
    convmf_k<3, 2, 9, 4, 128, 3, 1><<<dim3(51, 4, BB), dim3(256), 0, stream>>>(
        ftcl, wpctx, b_ctx, b_ctx, 192, 192, 12, gi, 512, 0, hsep, 192, nullptr);

    // z|r = sigmoid(conv gi) -> zrbuf  (N=384, TOTOCT=24, NOCT=3, MF=4)
    convmf_k<3, 4, 9, 16, 512, 2, 0><<<dim3(26, 8, BB), dim3(256), 0, stream>>>(
        gi, wpzr, b_z, b_r, 192, 384, 24, zrbuf, 384, 0, nullptr, 0, nullptr);

    // gi ch0..191 = r*h
    rh_k<<<dim3((BB * HWN * 24 + 255) / 256), dim3(256), 0, stream>>>(zrbuf, hsep, gi);

    // q = tanh(conv gi) -> qbuf  (N=192, TOTOCT=12, NOCT=3, MF=2)
    convmf_k<3, 2, 9, 16, 512, 3, 0><<<dim3(51, 4, BB), dim3(256), 0, stream>>>(
        gi, wpq, b_q, b_q, 192, 192, 12, qbuf, 192, 0, nullptr, 0, nullptr);

    // gi ch0..191 = (1-z)h + z q
    hnew_k<<<dim3((BB * HWN * 24 + 255) / 256), dim3(256), 0, stream>>>(zrbuf, hsep, qbuf, gi);

    // out = [dh(112); fh(4)] conv of h' -> f32 CF  (N=128, TOTOCT=8, NOCT=2, MF=2)
    convmf_k<2, 2, 9, 6, 512, 0, 2><<<dim3(51, 4, BB), dim3(256), 0, stream>>>(
        gi, wpdh, b_dh, b_fh, 112, 116, 8, nullptr, 0, 0, nullptr, 0, out);
}